// Round 2
// baseline (888.402 us; speedup 1.0000x reference)
//
#include <hip/hip_runtime.h>
#include <hip/hip_bf16.h>

// Glm4MoE: B=1,S=2048,D=1024, E=64,K=8,F=768, SF=768, C=512, ROUTED_SCALE=1
// Inputs/outputs are float32 (per reference). GEMMs run bf16 MFMA with f32
// accumulation; weights converted f32->bf16 on the fly during LDS staging.
//
// Pipeline:
//   memset(counts) -> x_to_bf16 -> router (f32, top8 + dispatch) ->
//   gemm_gu (experts z=0..63 + shared z=64): H = silu(X@Wg) * (X@Wu)  [bf16]
//   down_shared: out = Hs @ Wsd          (plain f32 stores, covers all)
//   down_routed: out += w * (H @ Wd)     (atomicAdd f32)

typedef unsigned int uint;
typedef unsigned short ushort;
typedef __bf16 v8bf __attribute__((ext_vector_type(8)));
typedef float v4f __attribute__((ext_vector_type(4)));

#define MFMA_BF16 __builtin_amdgcn_mfma_f32_16x16x32_bf16

#define NTOK 2048
#define DMODEL 1024
#define NEXP 64
#define TOPK 8
#define FFN 768
#define CAP 512

// LDS row stride (elements); 40*2B = 80B = multiple of 16 -> b128-aligned rows
#define LDSW 40

__device__ inline ushort f2bf(float f) {
    uint u = __float_as_uint(f);
    u = (u + 0x7FFFu + ((u >> 16) & 1u)) >> 16;
    return (ushort)u;
}
__device__ inline uint pkbf(float lo, float hi) {
    __hip_bfloat162 h = __float22bfloat162_rn(float2{lo, hi});
    uint u;
    __builtin_memcpy(&u, &h, 4);
    return u;
}

// ------------------------------------------------------------- x -> bf16 ----
__global__ __launch_bounds__(256) void x2bf_kernel(
    const float* __restrict__ X, ushort* __restrict__ Xb)
{
    int i = (blockIdx.x * 256 + threadIdx.x) * 4;
    float4 v = *(const float4*)(X + i);
    uint2 o;
    o.x = pkbf(v.x, v.y);
    o.y = pkbf(v.z, v.w);
    *(uint2*)(Xb + i) = o;
}

// ---------------------------------------------------------------- router ----
// one wave per token (f32 math so top-k matches the f32 reference):
// logits over 64 experts, exp(l-max), top-8 by repeated argmax, renorm.
__global__ __launch_bounds__(64) void router_kernel(
    const float* __restrict__ X, const float* __restrict__ RW,
    int* __restrict__ counts, int* __restrict__ tok_map,
    float* __restrict__ wt_map)
{
    const int t = blockIdx.x;
    const int lane = threadIdx.x;  // == expert id
    const float* xr = X + (size_t)t * DMODEL;
    const float* wr = RW + (size_t)lane * DMODEL;
    float sum = 0.f;
    for (int d = 0; d < DMODEL; d += 4) {
        float4 a = *(const float4*)(wr + d);
        float4 b = *(const float4*)(xr + d);
        sum += a.x * b.x + a.y * b.y + a.z * b.z + a.w * b.w;
    }
    float mx = sum;
    for (int off = 32; off; off >>= 1) mx = fmaxf(mx, __shfl_xor(mx, off));
    float p = __expf(sum - mx);  // softmax denom cancels in renorm

    float v = p;
    float my_p = 0.f;
    int my_e = 0;
    for (int it = 0; it < TOPK; ++it) {
        float m = v;
        int mi = lane;
        for (int off = 32; off; off >>= 1) {
            float om = __shfl_xor(m, off);
            int oi = __shfl_xor(mi, off);
            if (om > m || (om == m && oi < mi)) { m = om; mi = oi; }
        }
        if (lane == it) { my_p = m; my_e = mi; }
        if (lane == mi) v = -1.f;
    }
    float s = (lane < TOPK) ? my_p : 0.f;
    for (int off = 32; off; off >>= 1) s += __shfl_xor(s, off);
    if (lane < TOPK) {
        float w = my_p / s;   // stays f32 (x dtype is f32 in reference)
        int slot = atomicAdd(&counts[my_e], 1);
        if (slot < CAP) {
            tok_map[my_e * CAP + slot] = t;
            wt_map[my_e * CAP + slot] = w;
        }
    }
}

// ------------------------------------------------------------- gemm gate/up -
// Block tile: 128 rows x 64 cols of H, BK=32, 4 waves 2x2 (wave: 64x32).
// z in [0,64): routed expert e (rows gathered).  z==64: shared expert.
// A: bf16 Xb.  B: f32 weights, cvt->bf16 + transpose during staging.
__global__ __launch_bounds__(256) void gemm_gu(
    const ushort* __restrict__ Xb,
    const float* __restrict__ Wg_all, const float* __restrict__ Wu_all,
    const float* __restrict__ Wshared,  // (1024 x 1536): gate 0..767, up 768..1535
    ushort* __restrict__ H,             // [64][512][768] bf16
    ushort* __restrict__ Hs,            // [2048][768] bf16
    const int* __restrict__ tok_map, const int* __restrict__ counts)
{
    const int e = blockIdx.z;
    const bool sh = (e == NEXP);
    const int rows = sh ? NTOK : min(counts[e], CAP);
    const int mtile = blockIdx.y, ntile = blockIdx.x;
    if (mtile * 128 >= rows) return;

    const float* Wg;
    const float* Wu;
    int ldw;
    ushort* Hbase;
    if (sh) {
        Wg = Wshared + ntile * 64;
        Wu = Wshared + FFN + ntile * 64;
        ldw = 2 * FFN;
        Hbase = Hs;
    } else {
        Wg = Wg_all + (size_t)e * DMODEL * FFN + ntile * 64;
        Wu = Wu_all + (size_t)e * DMODEL * FFN + ntile * 64;
        ldw = FFN;
        Hbase = H + (size_t)e * CAP * FFN;
    }

    __shared__ ushort As[128 * LDSW];
    __shared__ ushort Bg[64 * LDSW];
    __shared__ ushort Bu[64 * LDSW];

    const int tid = threadIdx.x;
    const int ar = tid >> 1, ah = (tid & 1) * 16;
    const int gslot = mtile * 128 + ar;
    const ushort* aptr = nullptr;
    if (gslot < rows) {
        int row = sh ? gslot : tok_map[e * CAP + gslot];
        aptr = Xb + (size_t)row * DMODEL + ah;
    }
    const int bn2 = (tid & 31) * 2, bkg = (tid >> 5) * 4;
    const float* gptr = Wg + (size_t)bkg * ldw + bn2;
    const float* uptr = Wu + (size_t)bkg * ldw + bn2;

    const int lane = tid & 63, wv = tid >> 6;
    const int wm = (wv & 1) * 64, wn = (wv >> 1) * 32;
    const int lr = lane & 15, lq = lane >> 4;

    v4f accg[4][2] = {};
    v4f accu[4][2] = {};

    for (int k0 = 0; k0 < DMODEL; k0 += 32) {
        uint4 a0 = make_uint4(0, 0, 0, 0), a1 = make_uint4(0, 0, 0, 0);
        if (aptr) {
            a0 = *(const uint4*)(aptr + k0);
            a1 = *(const uint4*)(aptr + k0 + 8);
        }
        const float* gp = gptr + (size_t)k0 * ldw;
        const float* up = uptr + (size_t)k0 * ldw;
        float2 g0 = *(const float2*)(gp);
        float2 g1 = *(const float2*)(gp + ldw);
        float2 g2 = *(const float2*)(gp + 2 * ldw);
        float2 g3 = *(const float2*)(gp + 3 * ldw);
        float2 u0 = *(const float2*)(up);
        float2 u1 = *(const float2*)(up + ldw);
        float2 u2 = *(const float2*)(up + 2 * ldw);
        float2 u3 = *(const float2*)(up + 3 * ldw);
        __syncthreads();
        *(uint4*)&As[ar * LDSW + ah] = a0;
        *(uint4*)&As[ar * LDSW + ah + 8] = a1;
        {   // cvt + transpose-pack gate: Bt[n][k] bf16
            uint2 lo, hi;
            lo.x = pkbf(g0.x, g1.x); lo.y = pkbf(g2.x, g3.x);
            hi.x = pkbf(g0.y, g1.y); hi.y = pkbf(g2.y, g3.y);
            *(uint2*)&Bg[bn2 * LDSW + bkg] = lo;
            *(uint2*)&Bg[(bn2 + 1) * LDSW + bkg] = hi;
        }
        {   // cvt + transpose-pack up
            uint2 lo, hi;
            lo.x = pkbf(u0.x, u1.x); lo.y = pkbf(u2.x, u3.x);
            hi.x = pkbf(u0.y, u1.y); hi.y = pkbf(u2.y, u3.y);
            *(uint2*)&Bu[bn2 * LDSW + bkg] = lo;
            *(uint2*)&Bu[(bn2 + 1) * LDSW + bkg] = hi;
        }
        __syncthreads();

        v8bf a[4], bg[2], bu[2];
#pragma unroll
        for (int mi = 0; mi < 4; ++mi)
            a[mi] = *(const v8bf*)&As[(wm + mi * 16 + lr) * LDSW + lq * 8];
#pragma unroll
        for (int ni = 0; ni < 2; ++ni) {
            bg[ni] = *(const v8bf*)&Bg[(wn + ni * 16 + lr) * LDSW + lq * 8];
            bu[ni] = *(const v8bf*)&Bu[(wn + ni * 16 + lr) * LDSW + lq * 8];
        }
#pragma unroll
        for (int mi = 0; mi < 4; ++mi)
#pragma unroll
            for (int ni = 0; ni < 2; ++ni) {
                accg[mi][ni] = MFMA_BF16(a[mi], bg[ni], accg[mi][ni], 0, 0, 0);
                accu[mi][ni] = MFMA_BF16(a[mi], bu[ni], accu[mi][ni], 0, 0, 0);
            }
    }

#pragma unroll
    for (int mi = 0; mi < 4; ++mi)
#pragma unroll
        for (int ni = 0; ni < 2; ++ni)
#pragma unroll
            for (int r = 0; r < 4; ++r) {
                float g = accg[mi][ni][r];
                float u = accu[mi][ni][r];
                float h = (g / (1.f + __expf(-g))) * u;  // silu(g)*u
                int row = mtile * 128 + wm + mi * 16 + lq * 4 + r;
                int col = ntile * 64 + wn + ni * 16 + lr;
                Hbase[(size_t)row * FFN + col] = f2bf(h);
            }
}

// -------------------------------------------------------------- down shared -
// out[t][:] = Hs @ Wsd  (plain f32 stores; covers every output element)
__global__ __launch_bounds__(256) void down_shared(
    const ushort* __restrict__ Hs, const float* __restrict__ Wsd,
    float* __restrict__ Out)
{
    const int mtile = blockIdx.y, ntile = blockIdx.x;

    __shared__ ushort As[128 * LDSW];
    __shared__ ushort Bt[64 * LDSW];

    const int tid = threadIdx.x;
    const int ar = tid >> 1, ah = (tid & 1) * 16;
    const ushort* aptr = Hs + (size_t)(mtile * 128 + ar) * FFN + ah;
    const int bn2 = (tid & 31) * 2, bkg = (tid >> 5) * 4;
    const float* wptr = Wsd + (size_t)bkg * DMODEL + ntile * 64 + bn2;

    const int lane = tid & 63, wv = tid >> 6;
    const int wm = (wv & 1) * 64, wn = (wv >> 1) * 32;
    const int lr = lane & 15, lq = lane >> 4;

    v4f accv[4][2] = {};

    for (int k0 = 0; k0 < FFN; k0 += 32) {
        uint4 a0 = *(const uint4*)(aptr + k0);
        uint4 a1 = *(const uint4*)(aptr + k0 + 8);
        const float* wp = wptr + (size_t)k0 * DMODEL;
        float2 g0 = *(const float2*)(wp);
        float2 g1 = *(const float2*)(wp + DMODEL);
        float2 g2 = *(const float2*)(wp + 2 * DMODEL);
        float2 g3 = *(const float2*)(wp + 3 * DMODEL);
        __syncthreads();
        *(uint4*)&As[ar * LDSW + ah] = a0;
        *(uint4*)&As[ar * LDSW + ah + 8] = a1;
        {
            uint2 lo, hi;
            lo.x = pkbf(g0.x, g1.x); lo.y = pkbf(g2.x, g3.x);
            hi.x = pkbf(g0.y, g1.y); hi.y = pkbf(g2.y, g3.y);
            *(uint2*)&Bt[bn2 * LDSW + bkg] = lo;
            *(uint2*)&Bt[(bn2 + 1) * LDSW + bkg] = hi;
        }
        __syncthreads();

        v8bf a[4], b[2];
#pragma unroll
        for (int mi = 0; mi < 4; ++mi)
            a[mi] = *(const v8bf*)&As[(wm + mi * 16 + lr) * LDSW + lq * 8];
#pragma unroll
        for (int ni = 0; ni < 2; ++ni)
            b[ni] = *(const v8bf*)&Bt[(wn + ni * 16 + lr) * LDSW + lq * 8];
#pragma unroll
        for (int mi = 0; mi < 4; ++mi)
#pragma unroll
            for (int ni = 0; ni < 2; ++ni)
                accv[mi][ni] = MFMA_BF16(a[mi], b[ni], accv[mi][ni], 0, 0, 0);
    }

#pragma unroll
    for (int mi = 0; mi < 4; ++mi)
#pragma unroll
        for (int ni = 0; ni < 2; ++ni)
#pragma unroll
            for (int r = 0; r < 4; ++r) {
                int row = mtile * 128 + wm + mi * 16 + lq * 4 + r;
                int col = ntile * 64 + wn + ni * 16 + lr;
                Out[(size_t)row * DMODEL + col] = accv[mi][ni][r];
            }
}

// -------------------------------------------------------------- down routed -
// out[tok][:] += w * (H[e] @ Wd[e])  via f32 atomicAdd
__global__ __launch_bounds__(256) void down_routed(
    const ushort* __restrict__ H, const float* __restrict__ Wd_all,
    float* __restrict__ Out,
    const int* __restrict__ tok_map, const float* __restrict__ wt_map,
    const int* __restrict__ counts)
{
    const int e = blockIdx.z;
    const int rows = min(counts[e], CAP);
    const int mtile = blockIdx.y, ntile = blockIdx.x;
    if (mtile * 128 >= rows) return;

    const ushort* A = H + (size_t)e * CAP * FFN;
    const float* W = Wd_all + (size_t)e * FFN * DMODEL + ntile * 64;

    __shared__ ushort As[128 * LDSW];
    __shared__ ushort Bt[64 * LDSW];

    const int tid = threadIdx.x;
    const int ar = tid >> 1, ah = (tid & 1) * 16;
    const ushort* aptr = A + (size_t)(mtile * 128 + ar) * FFN + ah;  // pad rows are 0
    const int bn2 = (tid & 31) * 2, bkg = (tid >> 5) * 4;
    const float* wptr = W + (size_t)bkg * DMODEL + bn2;

    const int lane = tid & 63, wv = tid >> 6;
    const int wm = (wv & 1) * 64, wn = (wv >> 1) * 32;
    const int lr = lane & 15, lq = lane >> 4;

    v4f accv[4][2] = {};

    for (int k0 = 0; k0 < FFN; k0 += 32) {
        uint4 a0 = *(const uint4*)(aptr + k0);
        uint4 a1 = *(const uint4*)(aptr + k0 + 8);
        const float* wp = wptr + (size_t)k0 * DMODEL;
        float2 g0 = *(const float2*)(wp);
        float2 g1 = *(const float2*)(wp + DMODEL);
        float2 g2 = *(const float2*)(wp + 2 * DMODEL);
        float2 g3 = *(const float2*)(wp + 3 * DMODEL);
        __syncthreads();
        *(uint4*)&As[ar * LDSW + ah] = a0;
        *(uint4*)&As[ar * LDSW + ah + 8] = a1;
        {
            uint2 lo, hi;
            lo.x = pkbf(g0.x, g1.x); lo.y = pkbf(g2.x, g3.x);
            hi.x = pkbf(g0.y, g1.y); hi.y = pkbf(g2.y, g3.y);
            *(uint2*)&Bt[bn2 * LDSW + bkg] = lo;
            *(uint2*)&Bt[(bn2 + 1) * LDSW + bkg] = hi;
        }
        __syncthreads();

        v8bf a[4], b[2];
#pragma unroll
        for (int mi = 0; mi < 4; ++mi)
            a[mi] = *(const v8bf*)&As[(wm + mi * 16 + lr) * LDSW + lq * 8];
#pragma unroll
        for (int ni = 0; ni < 2; ++ni)
            b[ni] = *(const v8bf*)&Bt[(wn + ni * 16 + lr) * LDSW + lq * 8];
#pragma unroll
        for (int mi = 0; mi < 4; ++mi)
#pragma unroll
            for (int ni = 0; ni < 2; ++ni)
                accv[mi][ni] = MFMA_BF16(a[mi], b[ni], accv[mi][ni], 0, 0, 0);
    }

#pragma unroll
    for (int mi = 0; mi < 4; ++mi)
#pragma unroll
        for (int ni = 0; ni < 2; ++ni)
#pragma unroll
            for (int r = 0; r < 4; ++r) {
                int lrow = wm + mi * 16 + lq * 4 + r;
                int gslot = mtile * 128 + lrow;
                int col = ntile * 64 + wn + ni * 16 + lr;
                if (gslot < rows) {
                    int t = tok_map[e * CAP + gslot];
                    float w = wt_map[e * CAP + gslot];
                    atomicAdd(&Out[(size_t)t * DMODEL + col], w * accv[mi][ni][r]);
                }
            }
}

// ------------------------------------------------------------------ launch --
extern "C" void kernel_launch(void* const* d_in, const int* in_sizes, int n_in,
                              void* d_out, int out_size, void* d_ws, size_t ws_size,
                              hipStream_t stream)
{
    const float* x    = (const float*)d_in[0];  // (1,2048,1024)
    const float* rw   = (const float*)d_in[1];  // (64,1024)
    const float* wg   = (const float*)d_in[2];  // (64,1024,768)
    const float* wu   = (const float*)d_in[3];  // (64,1024,768)
    const float* wd   = (const float*)d_in[4];  // (64,768,1024)
    const float* wsgu = (const float*)d_in[5];  // (1024,1536)
    const float* wsd  = (const float*)d_in[6];  // (768,1024)
    float* out = (float*)d_out;

    char* ws = (char*)d_ws;
    int*    counts = (int*)(ws + 0);                 // 256 B
    int*    tok    = (int*)(ws + 4096);              // 128 KB
    float*  wt     = (float*)(ws + 139264);          // 128 KB
    ushort* Xb     = (ushort*)(ws + (1 << 20));      // 4 MB   [2048][1024] bf16
    ushort* H      = (ushort*)(ws + (8 << 20));      // 48 MB  [64][512][768] bf16
    ushort* Hs     = (ushort*)(ws + 58720256);       // 3 MB   [2048][768] bf16
    // total ws needed ~59 MB

    hipMemsetAsync(counts, 0, NEXP * sizeof(int), stream);

    x2bf_kernel<<<NTOK * DMODEL / 1024, 256, 0, stream>>>(x, Xb);
    router_kernel<<<NTOK, 64, 0, stream>>>(x, rw, counts, tok, wt);

    // gate/up: 12 n-tiles (768/64), 16 m-tiles (shared needs 2048 rows;
    // routed experts early-exit), 65 z (64 experts + shared)
    gemm_gu<<<dim3(12, 16, NEXP + 1), 256, 0, stream>>>(Xb, wg, wu, wsgu, H, Hs, tok, counts);

    // shared down: plain stores cover all of out (so no memset needed)
    down_shared<<<dim3(16, 16), 256, 0, stream>>>(Hs, wsd, out);

    // routed down: atomicAdd on top of shared
    down_routed<<<dim3(16, 4, NEXP), 256, 0, stream>>>(H, wd, out, tok, wt, counts);
}